// Round 4
// baseline (1499.886 us; speedup 1.0000x reference)
//
#include <hip/hip_runtime.h>

#define B_ 32
#define T_ 120
#define E_ 256
#define H_ 512
#define NSPAN 36960   // B_ * 1155

typedef __attribute__((ext_vector_type(8))) short short8;
typedef __attribute__((ext_vector_type(4))) short sshort4;
typedef __attribute__((ext_vector_type(4))) float f32x4;
typedef __attribute__((ext_vector_type(4))) unsigned int u32x4;
typedef unsigned long long ull;

__device__ __forceinline__ short f2bf(float x) {
    union { float f; unsigned u; } v; v.f = x;
    unsigned r = v.u + 0x7fffu + ((v.u >> 16) & 1u);
    return (short)(r >> 16);
}
__device__ __forceinline__ float bf2f(unsigned short x) {
    union { unsigned u; float f; } v; v.u = ((unsigned)x) << 16;
    return v.f;
}

// coherent (IC-visible) 16B load: one base reg-pair + compile-time byte offset
#define LDX4(dst, base, OFFS) \
    asm volatile("global_load_dwordx4 %0, %1, off offset:" OFFS " sc0 sc1" \
                 : "=v"(dst) : "v"(base))
#define RETRY2(ks, OFFS) \
    if (need & (1u << ks)) { LDX4(hr0[ks], hb0, OFFS); LDX4(hr1[ks], hb1, OFFS); }

// ---------------- gather tokens -> x bf16 (row m = t*32 + b) ----------------
__global__ void k_gather(const int* __restrict__ tokens, const float* __restrict__ emb,
                         short* __restrict__ xbf) {
    int m = blockIdx.x;              // 0..3839, m = t*32+b
    int t = m >> 5, b = m & 31;
    int tok = tokens[b * T_ + t];
    int e = threadIdx.x;             // 256
    xbf[(size_t)m * E_ + e] = f2bf(emb[(size_t)tok * E_ + e]);
}

// ---------------- fp32 -> bf16 convert ----------------
__global__ void k_convert(const float* __restrict__ src, short* __restrict__ dst, int n8) {
    int i = blockIdx.x * blockDim.x + threadIdx.x;
    if (i >= n8) return;
    const float4* s4 = (const float4*)src + (size_t)i * 2;
    float4 a = s4[0], b = s4[1];
    short8 o;
    o[0]=f2bf(a.x); o[1]=f2bf(a.y); o[2]=f2bf(a.z); o[3]=f2bf(a.w);
    o[4]=f2bf(b.x); o[5]=f2bf(b.y); o[6]=f2bf(b.z); o[7]=f2bf(b.w);
    *(short8*)(dst + (size_t)i * 8) = o;
}

__global__ void k_biascomb(const float* __restrict__ bf1, const float* __restrict__ bf2,
                           const float* __restrict__ bb1, const float* __restrict__ bb2,
                           float* __restrict__ out) {
    int i = blockIdx.x * 256 + threadIdx.x;   // 4096
    out[i] = (i < 2048) ? (bf1[i] + bf2[i]) : (bb1[i - 2048] + bb2[i - 2048]);
}

// ---------------- generic bf16 MFMA GEMM: out = A(MxK) @ W(NxK)^T + bias ----------------
template <int EPI>
__global__ void __launch_bounds__(256) k_gemm(const short* __restrict__ A,
                                              const short* __restrict__ W,
                                              const float* __restrict__ bias,
                                              float* __restrict__ outF,
                                              short* __restrict__ outB,
                                              int N, int K) {
    int w = threadIdx.x >> 6, l = threadIdx.x & 63;
    int la = l & 15, lb = l >> 4;
    int m0 = blockIdx.x * 64 + w * 16;
    int nb = blockIdx.y * 64;
    const short* Ap = A + (size_t)(m0 + la) * K + lb * 8;
    const short* Wp = W + (size_t)(nb + la) * K + lb * 8;
    f32x4 acc0 = {0.f,0.f,0.f,0.f}, acc1 = acc0, acc2 = acc0, acc3 = acc0;
    for (int k0 = 0; k0 < K; k0 += 32) {
        short8 a  = *(const short8*)(Ap + k0);
        short8 b0 = *(const short8*)(Wp + k0);
        short8 b1 = *(const short8*)(Wp + (size_t)16 * K + k0);
        short8 b2 = *(const short8*)(Wp + (size_t)32 * K + k0);
        short8 b3 = *(const short8*)(Wp + (size_t)48 * K + k0);
        acc0 = __builtin_amdgcn_mfma_f32_16x16x32_bf16(a, b0, acc0, 0, 0, 0);
        acc1 = __builtin_amdgcn_mfma_f32_16x16x32_bf16(a, b1, acc1, 0, 0, 0);
        acc2 = __builtin_amdgcn_mfma_f32_16x16x32_bf16(a, b2, acc2, 0, 0, 0);
        acc3 = __builtin_amdgcn_mfma_f32_16x16x32_bf16(a, b3, acc3, 0, 0, 0);
    }
    f32x4 accs[4] = {acc0, acc1, acc2, acc3};
    #pragma unroll
    for (int j = 0; j < 4; ++j) {
        int n = nb + j * 16 + la;
        float bv = bias[n];
        if (EPI == 2) {
            int mb = m0 + lb * 4;
            int t = mb >> 5, b0i = mb & 31;
            sshort4 pk;
            #pragma unroll
            for (int r = 0; r < 4; ++r) pk[r] = f2bf(accs[j][r] + bv);
            *(sshort4*)(outB + (((size_t)t * 4096 + n) << 5) + b0i) = pk;
        } else {
            #pragma unroll
            for (int r = 0; r < 4; ++r) {
                int m = m0 + lb * 4 + r;
                float v = accs[j][r] + bv;
                if (EPI == 0) outF[(size_t)m * N + n] = v;
                else          outB[(size_t)m * N + n] = f2bf(fmaxf(v, 0.f));
            }
        }
    }
}

// ---------------- dataflow bidirectional LSTM ----------------
// 64 blocks: dir = bid>>5, jslice = bid&31. No barriers/flags/acks: per-step
// 32KB h buffers pre-armed with 0xFF sentinel; producers fire packed
// write-through 8B stores; consumers poll MFMA fragments straight from IC.
__global__ void __launch_bounds__(256, 1) k_lstm(const short* __restrict__ xg,
                                                 const short* __restrict__ whh,
                                                 const short* __restrict__ hzero,
                                                 short* __restrict__ hsteps,
                                                 short* __restrict__ rnn) {
    __shared__ short hpack[4][32][4];
    int tid = threadIdx.x;
    int w = tid >> 6, l = tid & 63;
    int la = l & 15, lb = l >> 4;
    int bid = blockIdx.x;
    int dir = bid >> 5, jsl = bid & 31;
    int jw = jsl * 16 + w * 4;
    int gate = la >> 2;
    int row = dir * 2048 + gate * 512 + jw + (la & 3);   // gate-row index in [0,4096)

    // weight B-fragments in registers: wf[ks] = w[row][ks*32 + lb*8 .. +8]
    short8 wf[16];
    {
        const short* wr = whh + (size_t)row * 512 + lb * 8;
        #pragma unroll
        for (int ks = 0; ks < 16; ++ks) wf[ks] = *(const short8*)(wr + ks * 32);
    }

    float cst[2][4] = {{0.f,0.f,0.f,0.f},{0.f,0.f,0.f,0.f}};

    for (int s = 0; s < T_; ++s) {
        int t = dir ? (T_ - 1 - s) : s;
        const short* hb = (s == 0) ? hzero
                                   : (hsteps + ((size_t)(dir * T_ + (s - 1)) << 14));
        short* hn = hsteps + ((size_t)(dir * T_ + s) << 14);
        const short* hb0 = hb + la * 512 + lb * 8;
        const short* hb1 = hb0 + 16 * 512;

        // xg loads for this lane's gate-row (cached), issued first
        ull x0, x1;
        {
            const short* xgp = xg + (size_t)t * 131072 + (size_t)row * 32 + lb * 4;
            asm volatile("global_load_dwordx2 %0, %1, off" : "=v"(x0) : "v"(xgp));
            asm volatile("global_load_dwordx2 %0, %1, off offset:32" : "=v"(x1) : "v"(xgp));
        }

        // h fragment loads (IC-coherent), one base + imm offsets
        u32x4 hr0[16], hr1[16];
        LDX4(hr0[0],hb0,"0");   LDX4(hr0[1],hb0,"64");  LDX4(hr0[2],hb0,"128"); LDX4(hr0[3],hb0,"192");
        LDX4(hr0[4],hb0,"256"); LDX4(hr0[5],hb0,"320"); LDX4(hr0[6],hb0,"384"); LDX4(hr0[7],hb0,"448");
        LDX4(hr0[8],hb0,"512"); LDX4(hr0[9],hb0,"576"); LDX4(hr0[10],hb0,"640");LDX4(hr0[11],hb0,"704");
        LDX4(hr0[12],hb0,"768");LDX4(hr0[13],hb0,"832");LDX4(hr0[14],hb0,"896");LDX4(hr0[15],hb0,"960");
        LDX4(hr1[0],hb1,"0");   LDX4(hr1[1],hb1,"64");  LDX4(hr1[2],hb1,"128"); LDX4(hr1[3],hb1,"192");
        LDX4(hr1[4],hb1,"256"); LDX4(hr1[5],hb1,"320"); LDX4(hr1[6],hb1,"384"); LDX4(hr1[7],hb1,"448");
        LDX4(hr1[8],hb1,"512"); LDX4(hr1[9],hb1,"576"); LDX4(hr1[10],hb1,"640");LDX4(hr1[11],hb1,"704");
        LDX4(hr1[12],hb1,"768");LDX4(hr1[13],hb1,"832");LDX4(hr1[14],hb1,"896");LDX4(hr1[15],hb1,"960");
        asm volatile("s_waitcnt vmcnt(0)" ::: "memory");
        __builtin_amdgcn_sched_barrier(0);

        float xv[2][4];
        #pragma unroll
        for (int r = 0; r < 4; ++r) {
            xv[0][r] = bf2f((unsigned short)((x0 >> (16 * r)) & 0xffffu));
            xv[1][r] = bf2f((unsigned short)((x1 >> (16 * r)) & 0xffffu));
        }

        f32x4 ae0 = {0.f,0.f,0.f,0.f}, ao0 = ae0, ae1 = ae0, ao1 = ae0;
        unsigned need = 0xFFFFu;
        int tries = 0;
        while (true) {
            unsigned got = 0;
            #pragma unroll
            for (int ks = 0; ks < 16; ++ks) {
                if (need & (1u << ks)) {
                    u32x4 f0 = hr0[ks], f1 = hr1[ks];
                    int bad = (f0[0] == 0xFFFFFFFFu) || (f0[2] == 0xFFFFFFFFu) ||
                              (f1[0] == 0xFFFFFFFFu) || (f1[2] == 0xFFFFFFFFu);
                    if (!__any(bad)) {
                        short8 s0 = __builtin_bit_cast(short8, f0);
                        short8 s1 = __builtin_bit_cast(short8, f1);
                        if (ks & 1) {
                            ao0 = __builtin_amdgcn_mfma_f32_16x16x32_bf16(s0, wf[ks], ao0, 0, 0, 0);
                            ao1 = __builtin_amdgcn_mfma_f32_16x16x32_bf16(s1, wf[ks], ao1, 0, 0, 0);
                        } else {
                            ae0 = __builtin_amdgcn_mfma_f32_16x16x32_bf16(s0, wf[ks], ae0, 0, 0, 0);
                            ae1 = __builtin_amdgcn_mfma_f32_16x16x32_bf16(s1, wf[ks], ae1, 0, 0, 0);
                        }
                        got |= 1u << ks;
                    }
                }
            }
            need &= ~got;
            if (!need) break;
            if (++tries > (1 << 17)) break;   // diagnostic escape: leaves NaNs, terminates
            RETRY2(0,"0");   RETRY2(1,"64");  RETRY2(2,"128"); RETRY2(3,"192");
            RETRY2(4,"256"); RETRY2(5,"320"); RETRY2(6,"384"); RETRY2(7,"448");
            RETRY2(8,"512"); RETRY2(9,"576"); RETRY2(10,"640");RETRY2(11,"704");
            RETRY2(12,"768");RETRY2(13,"832");RETRY2(14,"896");RETRY2(15,"960");
            asm volatile("s_waitcnt vmcnt(0)" ::: "memory");
            __builtin_amdgcn_sched_barrier(0);
        }
        f32x4 a0 = ae0 + ao0, a1 = ae1 + ao1;

        float val[2][4];
        #pragma unroll
        for (int mt = 0; mt < 2; ++mt) {
            #pragma unroll
            for (int r = 0; r < 4; ++r) {
                float x = (mt ? a1[r] : a0[r]) + xv[mt][r];
                val[mt][r] = (gate == 2) ? (1.f - 2.f / (1.f + __expf(2.f * x)))
                                         : (1.f / (1.f + __expf(-x)));
            }
        }

        #pragma unroll
        for (int mt = 0; mt < 2; ++mt) {
            #pragma unroll
            for (int r = 0; r < 4; ++r) {
                float v = val[mt][r];
                float vf = __shfl_xor(v, 4);
                float vg = __shfl_xor(v, 8);
                float vo = __shfl_xor(v, 12);
                if (la < 4) {   // gate-0 lanes: v=sig(i), vf=sig(f), vg=tanh(g), vo=sig(o)
                    float c = vf * cst[mt][r] + v * vg;
                    cst[mt][r] = c;
                    float h = vo * (1.f - 2.f / (1.f + __expf(2.f * c)));
                    hpack[w][mt * 16 + lb * 4 + r][la] = f2bf(h);
                }
            }
        }
        __builtin_amdgcn_wave_barrier();
        if (l < 32) {
            ull pk = *(const ull*)&hpack[w][l][0];
            short* hp = hn + (size_t)l * 512 + jw;
            asm volatile("global_store_dwordx2 %0, %1, off sc0 sc1" :: "v"(hp), "v"(pk) : "memory");
            *(ull*)(rnn + ((size_t)l * T_ + t) * 1024 + dir * 512 + jw) = pk;
        }
        __builtin_amdgcn_wave_barrier();
    }
}

// ---------------- LayerNorm (wave per row of 512) ----------------
__global__ void k_ln(const float* __restrict__ h2, const float* __restrict__ gam,
                     const float* __restrict__ bet, float* __restrict__ tr) {
    int w = threadIdx.x >> 6, l = threadIdx.x & 63;
    size_t row = (size_t)blockIdx.x * 4 + w;
    const float* x = h2 + row * 512;
    float v[8], s = 0.f, s2 = 0.f;
    #pragma unroll
    for (int i = 0; i < 8; ++i) { v[i] = x[l + 64 * i]; s += v[i]; s2 += v[i] * v[i]; }
    #pragma unroll
    for (int off = 32; off; off >>= 1) { s += __shfl_xor(s, off); s2 += __shfl_xor(s2, off); }
    float mu = s * (1.f / 512.f);
    float var = s2 * (1.f / 512.f) - mu * mu;
    float rstd = 1.f / sqrtf(var + 1e-5f);
    float* o = tr + row * 512;
    #pragma unroll
    for (int i = 0; i < 8; ++i) { int k = l + 64 * i; o[k] = (v[i] - mu) * rstd * gam[k] + bet[k]; }
}

// ---------------- cumsum over t (block per batch, thread per feature) ----------------
__global__ void k_cumsum(const float* __restrict__ tr, float* __restrict__ cs) {
    int b = blockIdx.x, f = threadIdx.x;  // 512 threads
    cs[((size_t)b * 121) * 512 + f] = 0.f;
    const float* src = tr + ((size_t)b * 120) * 512 + f;
    float* dst = cs + ((size_t)b * 121 + 1) * 512 + f;
    float run = 0.f;
    for (int t0 = 0; t0 < 120; t0 += 8) {
        float v[8];
        #pragma unroll
        for (int i = 0; i < 8; ++i) v[i] = src[(size_t)(t0 + i) * 512];
        #pragma unroll
        for (int i = 0; i < 8; ++i) { run += v[i]; dst[(size_t)(t0 + i) * 512] = run; }
    }
}

// ---------------- spans + label GEMM (wave per span) ----------------
__global__ void __launch_bounds__(256) k_span(const float* __restrict__ cs,
                                              const float* __restrict__ lw,
                                              const float* __restrict__ lbias,
                                              float* __restrict__ out) {
    __shared__ float wl[20][512];
    for (int idx = threadIdx.x; idx < 20 * 512; idx += 256) {
        int c = idx >> 9, k = idx & 511;
        wl[c][k] = lw[(size_t)k * 20 + c];
    }
    __syncthreads();
    int w = threadIdx.x >> 6, l = threadIdx.x & 63;
    int nw = gridDim.x * 4;
    for (int sp = blockIdx.x * 4 + w; sp < NSPAN; sp += nw) {
        int b = sp / 1155, s = sp - b * 1155;
        int beg, len;
        if (s < 1110) { beg = s / 10; len = s - beg * 10 + 1; }
        else {
            int t2 = s - 1110; beg = 111; int ll = 9;
            while (t2 >= ll) { t2 -= ll; --ll; ++beg; }
            len = t2 + 1;
        }
        int end = beg + len;
        const float* ce = cs + ((size_t)b * 121 + end) * 512;
        const float* cb = cs + ((size_t)b * 121 + beg) * 512;
        float inv = 1.f / (float)len;
        float p[20];
        #pragma unroll
        for (int c = 0; c < 20; ++c) p[c] = 0.f;
        #pragma unroll
        for (int i = 0; i < 8; ++i) {
            int k = l + 64 * i;
            float d = (ce[k] - cb[k]) * inv;
            #pragma unroll
            for (int c = 0; c < 20; ++c) p[c] += d * wl[c][k];
        }
        #pragma unroll
        for (int off = 32; off; off >>= 1) {
            #pragma unroll
            for (int c = 0; c < 20; ++c) p[c] += __shfl_xor(p[c], off);
        }
        if (l == 0) {
            float* o = out + (size_t)sp * 20;
            #pragma unroll
            for (int c = 0; c < 20; ++c) o[c] = p[c] + lbias[c];
        }
    }
}

// ---------------- column-wise logsumexp over 36960 rows ----------------
__global__ void __launch_bounds__(256) k_lsepart(const float* __restrict__ logits,
                                                 float2* __restrict__ part) {
    float m[20], sm[20];
    #pragma unroll
    for (int c = 0; c < 20; ++c) { m[c] = -1e30f; sm[c] = 0.f; }
    for (int row = blockIdx.x * 256 + threadIdx.x; row < NSPAN; row += gridDim.x * 256) {
        const float* r = logits + (size_t)row * 20;
        #pragma unroll
        for (int c = 0; c < 20; ++c) {
            float x = r[c];
            float nm = fmaxf(m[c], x);
            sm[c] = sm[c] * expf(m[c] - nm) + expf(x - nm);
            m[c] = nm;
        }
    }
    __shared__ float2 red[256][20];
    #pragma unroll
    for (int c = 0; c < 20; ++c) red[threadIdx.x][c] = make_float2(m[c], sm[c]);
    __syncthreads();
    for (int st = 128; st; st >>= 1) {
        if (threadIdx.x < st) {
            #pragma unroll
            for (int c = 0; c < 20; ++c) {
                float2 a = red[threadIdx.x][c], b = red[threadIdx.x + st][c];
                float nm = fmaxf(a.x, b.x);
                float ss = a.y * expf(a.x - nm) + b.y * expf(b.x - nm);
                red[threadIdx.x][c] = make_float2(nm, ss);
            }
        }
        __syncthreads();
    }
    if (threadIdx.x < 20) part[(size_t)blockIdx.x * 20 + threadIdx.x] = red[0][threadIdx.x];
}

__global__ void k_lsefin(const float2* __restrict__ part, int nparts, float* __restrict__ lse) {
    int c = threadIdx.x;
    if (c >= 20) return;
    float m = -1e30f, s = 0.f;
    for (int i = 0; i < nparts; ++i) {
        float2 a = part[(size_t)i * 20 + c];
        float nm = fmaxf(m, a.x);
        s = s * expf(m - nm) + a.y * expf(a.x - nm);
        m = nm;
    }
    lse[c] = m + logf(s);
}

__global__ void k_sub(float* __restrict__ out, const float* __restrict__ lse) {
    int i = blockIdx.x * 256 + threadIdx.x;
    if (i < NSPAN * 20) out[i] -= lse[i % 20];
}

// ---------------- launch ----------------
extern "C" void kernel_launch(void* const* d_in, const int* in_sizes, int n_in,
                              void* d_out, int out_size, void* d_ws, size_t ws_size,
                              hipStream_t stream) {
    (void)in_sizes; (void)n_in; (void)out_size; (void)ws_size;
    const int*   tokens = (const int*)  d_in[0];
    const float* emb    = (const float*)d_in[1];
    const float* w_ih_f = (const float*)d_in[2];
    const float* w_hh_f = (const float*)d_in[3];
    const float* b_ih_f = (const float*)d_in[4];
    const float* b_hh_f = (const float*)d_in[5];
    const float* w_ih_b = (const float*)d_in[6];
    const float* w_hh_b = (const float*)d_in[7];
    const float* b_ih_b = (const float*)d_in[8];
    const float* b_hh_b = (const float*)d_in[9];
    const float* lin1_w = (const float*)d_in[10];
    const float* lin1_b = (const float*)d_in[11];
    const float* lin2_w = (const float*)d_in[12];
    const float* lin2_b = (const float*)d_in[13];
    const float* ln_g   = (const float*)d_in[14];
    const float* ln_b   = (const float*)d_in[15];
    const float* label_w= (const float*)d_in[16];
    const float* label_b= (const float*)d_in[17];
    float* out = (float*)d_out;

    char* ws = (char*)d_ws;
    size_t off = 0;
    auto alloc = [&](size_t bytes) { char* p = ws + off; off += (bytes + 255) & ~size_t(255); return p; };
    // persistent-lifetime regions (total ~57 MB; R2's proven-fit was 76.9 MB)
    short*  xbf   = (short*)alloc(3840ull * 256 * 2);
    short*  wihbf = (short*)alloc(4096ull * 256 * 2);
    short*  whhbf = (short*)alloc(2ull * 2048 * 512 * 2);   // dead after k_lstm
    short*  l1wbf = (short*)alloc(512ull * 1024 * 2);
    short*  l2wbf = (short*)alloc(512ull * 512 * 2);
    float*  biasc = (float*)alloc(4096ull * 4);
    short*  xg    = (short*)alloc(120ull * 4096 * 32 * 2);  // dead after k_lstm
    short*  hzero = (short*)alloc(32ull * 512 * 2);
    short*  hsteps= (short*)alloc(2ull * 120 * 32 * 512 * 2); // dead after k_lstm
    short*  rnn   = (short*)alloc(3840ull * 1024 * 2);
    float2* part  = (float2*)alloc(120ull * 20 * 8);
    float*  lse   = (float*)alloc(256);
    // overlays onto dead regions (strict stream ordering guarantees safety)
    short*  h1    = (short*)whhbf;          // 3.93 MB <= 4.19 MB, written after k_lstm
    float*  h2    = (float*)hsteps;         // 7.86 MB == 7.86 MB, written after k_lstm
    float*  tr    = (float*)xg;             // 7.86 MB <= 31.4 MB, written after k_lstm
    float*  cs    = (float*)((char*)xg + 8ull * 1024 * 1024);  // 7.93 MB, still inside xg

    hipMemsetAsync(hzero, 0x00, 32ull * 512 * 2, stream);
    hipMemsetAsync(hsteps, 0xFF, 2ull * 120 * 32 * 512 * 2, stream);

    k_gather<<<3840, 256, 0, stream>>>(tokens, emb, xbf);
    int n8;
    n8 = 2048 * 256 / 8; k_convert<<<(n8 + 255) / 256, 256, 0, stream>>>(w_ih_f, wihbf, n8);
    n8 = 2048 * 256 / 8; k_convert<<<(n8 + 255) / 256, 256, 0, stream>>>(w_ih_b, wihbf + 2048ull * 256, n8);
    n8 = 2048 * 512 / 8; k_convert<<<(n8 + 255) / 256, 256, 0, stream>>>(w_hh_f, whhbf, n8);
    n8 = 2048 * 512 / 8; k_convert<<<(n8 + 255) / 256, 256, 0, stream>>>(w_hh_b, whhbf + 2048ull * 512, n8);
    n8 = 512 * 1024 / 8; k_convert<<<(n8 + 255) / 256, 256, 0, stream>>>(lin1_w, l1wbf, n8);
    n8 = 512 * 512 / 8;  k_convert<<<(n8 + 255) / 256, 256, 0, stream>>>(lin2_w, l2wbf, n8);
    k_biascomb<<<16, 256, 0, stream>>>(b_ih_f, b_hh_f, b_ih_b, b_hh_b, biasc);

    // xg[t][g(4096)][b] = x @ [w_ih_f; w_ih_b]^T + (b_ih + b_hh)
    k_gemm<2><<<dim3(60, 64), 256, 0, stream>>>(xbf, wihbf, biasc, nullptr, xg, 4096, 256);
    // recurrence -> rnn[b*T+t][1024] (fwd | bwd)
    k_lstm<<<64, 256, 0, stream>>>(xg, whhbf, hzero, hsteps, rnn);
    // lin1 + relu -> bf16   (h1 overlays whhbf)
    k_gemm<1><<<dim3(60, 8), 256, 0, stream>>>(rnn, l1wbf, lin1_b, nullptr, h1, 512, 1024);
    // lin2 -> fp32          (h2 overlays hsteps)
    k_gemm<0><<<dim3(60, 8), 256, 0, stream>>>(h1, l2wbf, lin2_b, h2, nullptr, 512, 512);
    k_ln<<<960, 256, 0, stream>>>(h2, ln_g, ln_b, tr);
    k_cumsum<<<32, 512, 0, stream>>>(tr, cs);
    k_span<<<512, 256, 0, stream>>>(cs, label_w, label_b, out);
    k_lsepart<<<120, 256, 0, stream>>>(out, part);
    k_lsefin<<<1, 32, 0, stream>>>(part, 120, lse);
    k_sub<<<(NSPAN * 20 + 255) / 256, 256, 0, stream>>>(out, lse);
}

// Round 5
// 1151.991 us; speedup vs baseline: 1.3020x; 1.3020x over previous
//
#include <hip/hip_runtime.h>

#define B_ 32
#define T_ 120
#define E_ 256
#define H_ 512
#define NSPAN 36960   // B_ * 1155

typedef __attribute__((ext_vector_type(8))) short short8;
typedef __attribute__((ext_vector_type(4))) short sshort4;
typedef __attribute__((ext_vector_type(4))) float f32x4;
typedef __attribute__((ext_vector_type(4))) unsigned int u32x4;
typedef unsigned long long ull;

__device__ __forceinline__ short f2bf(float x) {
    union { float f; unsigned u; } v; v.f = x;
    unsigned r = v.u + 0x7fffu + ((v.u >> 16) & 1u);
    return (short)(r >> 16);
}
__device__ __forceinline__ float bf2f(unsigned short x) {
    union { unsigned u; float f; } v; v.u = ((unsigned)x) << 16;
    return v.f;
}

// coherent (IC-visible) 16B load: base reg-pair + compile-time byte offset
#define LDX4(dst, base, OFFS) \
    asm volatile("global_load_dwordx4 %0, %1, off offset:" OFFS " sc0 sc1" \
                 : "=v"(dst) : "v"(base))

// ---------------- gather tokens -> x bf16 (row m = t*32 + b) ----------------
__global__ void k_gather(const int* __restrict__ tokens, const float* __restrict__ emb,
                         short* __restrict__ xbf) {
    int m = blockIdx.x;              // 0..3839, m = t*32+b
    int t = m >> 5, b = m & 31;
    int tok = tokens[b * T_ + t];
    int e = threadIdx.x;             // 256
    xbf[(size_t)m * E_ + e] = f2bf(emb[(size_t)tok * E_ + e]);
}

// ---------------- fp32 -> bf16 convert ----------------
__global__ void k_convert(const float* __restrict__ src, short* __restrict__ dst, int n8) {
    int i = blockIdx.x * blockDim.x + threadIdx.x;
    if (i >= n8) return;
    const float4* s4 = (const float4*)src + (size_t)i * 2;
    float4 a = s4[0], b = s4[1];
    short8 o;
    o[0]=f2bf(a.x); o[1]=f2bf(a.y); o[2]=f2bf(a.z); o[3]=f2bf(a.w);
    o[4]=f2bf(b.x); o[5]=f2bf(b.y); o[6]=f2bf(b.z); o[7]=f2bf(b.w);
    *(short8*)(dst + (size_t)i * 8) = o;
}

__global__ void k_biascomb(const float* __restrict__ bf1, const float* __restrict__ bf2,
                           const float* __restrict__ bb1, const float* __restrict__ bb2,
                           float* __restrict__ out) {
    int i = blockIdx.x * 256 + threadIdx.x;   // 4096
    out[i] = (i < 2048) ? (bf1[i] + bf2[i]) : (bb1[i - 2048] + bb2[i - 2048]);
}

// ---------------- generic bf16 MFMA GEMM: out = A(MxK) @ W(NxK)^T + bias ----------------
template <int EPI>
__global__ void __launch_bounds__(256) k_gemm(const short* __restrict__ A,
                                              const short* __restrict__ W,
                                              const float* __restrict__ bias,
                                              float* __restrict__ outF,
                                              short* __restrict__ outB,
                                              int N, int K) {
    int w = threadIdx.x >> 6, l = threadIdx.x & 63;
    int la = l & 15, lb = l >> 4;
    int m0 = blockIdx.x * 64 + w * 16;
    int nb = blockIdx.y * 64;
    const short* Ap = A + (size_t)(m0 + la) * K + lb * 8;
    const short* Wp = W + (size_t)(nb + la) * K + lb * 8;
    f32x4 acc0 = {0.f,0.f,0.f,0.f}, acc1 = acc0, acc2 = acc0, acc3 = acc0;
    for (int k0 = 0; k0 < K; k0 += 32) {
        short8 a  = *(const short8*)(Ap + k0);
        short8 b0 = *(const short8*)(Wp + k0);
        short8 b1 = *(const short8*)(Wp + (size_t)16 * K + k0);
        short8 b2 = *(const short8*)(Wp + (size_t)32 * K + k0);
        short8 b3 = *(const short8*)(Wp + (size_t)48 * K + k0);
        acc0 = __builtin_amdgcn_mfma_f32_16x16x32_bf16(a, b0, acc0, 0, 0, 0);
        acc1 = __builtin_amdgcn_mfma_f32_16x16x32_bf16(a, b1, acc1, 0, 0, 0);
        acc2 = __builtin_amdgcn_mfma_f32_16x16x32_bf16(a, b2, acc2, 0, 0, 0);
        acc3 = __builtin_amdgcn_mfma_f32_16x16x32_bf16(a, b3, acc3, 0, 0, 0);
    }
    f32x4 accs[4] = {acc0, acc1, acc2, acc3};
    #pragma unroll
    for (int j = 0; j < 4; ++j) {
        int n = nb + j * 16 + la;
        float bv = bias[n];
        if (EPI == 2) {
            int mb = m0 + lb * 4;
            int t = mb >> 5, b0i = mb & 31;
            sshort4 pk;
            #pragma unroll
            for (int r = 0; r < 4; ++r) pk[r] = f2bf(accs[j][r] + bv);
            *(sshort4*)(outB + (((size_t)t * 4096 + n) << 5) + b0i) = pk;
        } else {
            #pragma unroll
            for (int r = 0; r < 4; ++r) {
                int m = m0 + lb * 4 + r;
                float v = accs[j][r] + bv;
                if (EPI == 0) outF[(size_t)m * N + n] = v;
                else          outB[(size_t)m * N + n] = f2bf(fmaxf(v, 0.f));
            }
        }
    }
}

// ---------------- flag-dataflow bidirectional LSTM ----------------
// 64 blocks: dir = bid>>5, jslice = bid&31. Per step: producer stores its
// 1KB h-slice (sc0 sc1) -> vmcnt(0) -> syncthreads -> plain flag store.
// Consumer polls 32 flags (4B/lane), then loads fragments ONCE, direct to
// registers, in a counted-vmcnt 4-batch pipeline.
__global__ void __launch_bounds__(256, 1) k_lstm(const short* __restrict__ xg,
                                                 const short* __restrict__ whh,
                                                 const short* __restrict__ hzero,
                                                 short* __restrict__ hsteps,
                                                 short* __restrict__ rnn,
                                                 int* __restrict__ flags) {
    __shared__ short hpack[4][32][4];
    int tid = threadIdx.x;
    int w = tid >> 6, l = tid & 63;
    int la = l & 15, lb = l >> 4;
    int bid = blockIdx.x;
    int dir = bid >> 5, jsl = bid & 31;
    int jw = jsl * 16 + w * 4;
    int gate = la >> 2;
    int row = dir * 2048 + gate * 512 + jw + (la & 3);   // gate-row index in [0,4096)

    // weight B-fragments in registers: wf[ks] = w[row][ks*32 + lb*8 .. +8]
    short8 wf[16];
    {
        const short* wr = whh + (size_t)row * 512 + lb * 8;
        #pragma unroll
        for (int ks = 0; ks < 16; ++ks) wf[ks] = *(const short8*)(wr + ks * 32);
    }

    float cst[2][4] = {{0.f,0.f,0.f,0.f},{0.f,0.f,0.f,0.f}};

#define LOADB(F0s, F1s, O0, O1, O2, O3) \
    LDX4(F0s[0], hb0, O0); LDX4(F1s[0], hb1, O0); \
    LDX4(F0s[1], hb0, O1); LDX4(F1s[1], hb1, O1); \
    LDX4(F0s[2], hb0, O2); LDX4(F1s[2], hb1, O2); \
    LDX4(F0s[3], hb0, O3); LDX4(F1s[3], hb1, O3)

#define PROCB(F0s, F1s, K0) do { \
    _Pragma("unroll") \
    for (int i = 0; i < 4; ++i) { \
        short8 s0 = __builtin_bit_cast(short8, F0s[i]); \
        short8 s1 = __builtin_bit_cast(short8, F1s[i]); \
        if (((K0) + i) & 1) { \
            ao0 = __builtin_amdgcn_mfma_f32_16x16x32_bf16(s0, wf[(K0) + i], ao0, 0, 0, 0); \
            ao1 = __builtin_amdgcn_mfma_f32_16x16x32_bf16(s1, wf[(K0) + i], ao1, 0, 0, 0); \
        } else { \
            ae0 = __builtin_amdgcn_mfma_f32_16x16x32_bf16(s0, wf[(K0) + i], ae0, 0, 0, 0); \
            ae1 = __builtin_amdgcn_mfma_f32_16x16x32_bf16(s1, wf[(K0) + i], ae1, 0, 0, 0); \
        } \
    } \
} while (0)

    for (int s = 0; s < T_; ++s) {
        int t = dir ? (T_ - 1 - s) : s;
        const short* hb = (s == 0) ? hzero
                                   : (hsteps + ((size_t)(dir * T_ + (s - 1)) << 14));
        short* hn = hsteps + ((size_t)(dir * T_ + s) << 14);
        const short* hb0 = hb + la * 512 + lb * 8;
        const short* hb1 = hb0 + 16 * 512;

        // xg loads for this lane's gate-row (cached), issued first
        ull x0, x1;
        {
            const short* xgp = xg + (size_t)t * 131072 + (size_t)row * 32 + lb * 4;
            asm volatile("global_load_dwordx2 %0, %1, off" : "=v"(x0) : "v"(xgp));
            asm volatile("global_load_dwordx2 %0, %1, off offset:32" : "=v"(x1) : "v"(xgp));
        }

        // wait for this dir's 32 producer flags of step s-1
        if (s > 0) {
            const int* fp = flags + (dir * T_ + (s - 1)) * 32;
            unsigned r;
            do {
                int f;
                asm volatile("global_load_dword %0, %1, off sc0 sc1\n\ts_waitcnt vmcnt(0)"
                             : "=v"(f) : "v"(fp + (l & 31)) : "memory");
                ull bal = __ballot(f != 0);
                r = (unsigned)bal & (unsigned)(bal >> 32);
            } while (r != 0xFFFFFFFFu);
        } else {
            asm volatile("s_waitcnt vmcnt(0)" ::: "memory");
        }
        __builtin_amdgcn_sched_barrier(0);

        // fragment pipeline: 16 chunks in 4 batches, data valid (flags ack'd)
        f32x4 ae0 = {0.f,0.f,0.f,0.f}, ao0 = ae0, ae1 = ae0, ao1 = ae0;
        {
            u32x4 fa0[4], fa1[4], fb0[4], fb1[4];
            LOADB(fa0, fa1, "0", "64", "128", "192");       // chunks 0-3
            LOADB(fb0, fb1, "256", "320", "384", "448");    // chunks 4-7
            asm volatile("s_waitcnt vmcnt(8)" ::: "memory");
            __builtin_amdgcn_sched_barrier(0);
            PROCB(fa0, fa1, 0);
            LOADB(fa0, fa1, "512", "576", "640", "704");    // chunks 8-11
            asm volatile("s_waitcnt vmcnt(8)" ::: "memory");
            __builtin_amdgcn_sched_barrier(0);
            PROCB(fb0, fb1, 4);
            LOADB(fb0, fb1, "768", "832", "896", "960");    // chunks 12-15
            asm volatile("s_waitcnt vmcnt(8)" ::: "memory");
            __builtin_amdgcn_sched_barrier(0);
            PROCB(fa0, fa1, 8);
            asm volatile("s_waitcnt vmcnt(0)" ::: "memory");
            __builtin_amdgcn_sched_barrier(0);
            PROCB(fb0, fb1, 12);
        }
        f32x4 a0 = ae0 + ao0, a1 = ae1 + ao1;

        float xv[2][4];
        #pragma unroll
        for (int r = 0; r < 4; ++r) {
            xv[0][r] = bf2f((unsigned short)((x0 >> (16 * r)) & 0xffffu));
            xv[1][r] = bf2f((unsigned short)((x1 >> (16 * r)) & 0xffffu));
        }

        float val[2][4];
        #pragma unroll
        for (int mt = 0; mt < 2; ++mt) {
            #pragma unroll
            for (int r = 0; r < 4; ++r) {
                float x = (mt ? a1[r] : a0[r]) + xv[mt][r];
                val[mt][r] = (gate == 2) ? (1.f - 2.f / (1.f + __expf(2.f * x)))
                                         : (1.f / (1.f + __expf(-x)));
            }
        }

        #pragma unroll
        for (int mt = 0; mt < 2; ++mt) {
            #pragma unroll
            for (int r = 0; r < 4; ++r) {
                float v = val[mt][r];
                float vf = __shfl_xor(v, 4);
                float vg = __shfl_xor(v, 8);
                float vo = __shfl_xor(v, 12);
                if (la < 4) {   // gate-0 lanes: v=sig(i), vf=sig(f), vg=tanh(g), vo=sig(o)
                    float c = vf * cst[mt][r] + v * vg;
                    cst[mt][r] = c;
                    float h = vo * (1.f - 2.f / (1.f + __expf(2.f * c)));
                    hpack[w][mt * 16 + lb * 4 + r][la] = f2bf(h);
                }
            }
        }
        __builtin_amdgcn_wave_barrier();
        ull pk = 0;
        if (l < 32) {
            pk = *(const ull*)&hpack[w][l][0];
            short* hp = hn + (size_t)l * 512 + jw;
            asm volatile("global_store_dwordx2 %0, %1, off sc0 sc1" :: "v"(hp), "v"(pk) : "memory");
        }
        asm volatile("s_waitcnt vmcnt(0)" ::: "memory");   // h stores ack'd at IC
        __syncthreads();                                   // all 4 waves done
        if (tid == 0) {
            int one = 1;
            asm volatile("global_store_dword %0, %1, off sc0 sc1"
                         :: "v"(flags + (dir * T_ + s) * 32 + jsl), "v"(one) : "memory");
        }
        // rnn store off the critical path (plain cached)
        if (l < 32)
            *(ull*)(rnn + ((size_t)l * T_ + t) * 1024 + dir * 512 + jw) = pk;
    }
#undef LOADB
#undef PROCB
}

// ---------------- LayerNorm (wave per row of 512) ----------------
__global__ void k_ln(const float* __restrict__ h2, const float* __restrict__ gam,
                     const float* __restrict__ bet, float* __restrict__ tr) {
    int w = threadIdx.x >> 6, l = threadIdx.x & 63;
    size_t row = (size_t)blockIdx.x * 4 + w;
    const float* x = h2 + row * 512;
    float v[8], s = 0.f, s2 = 0.f;
    #pragma unroll
    for (int i = 0; i < 8; ++i) { v[i] = x[l + 64 * i]; s += v[i]; s2 += v[i] * v[i]; }
    #pragma unroll
    for (int off = 32; off; off >>= 1) { s += __shfl_xor(s, off); s2 += __shfl_xor(s2, off); }
    float mu = s * (1.f / 512.f);
    float var = s2 * (1.f / 512.f) - mu * mu;
    float rstd = 1.f / sqrtf(var + 1e-5f);
    float* o = tr + row * 512;
    #pragma unroll
    for (int i = 0; i < 8; ++i) { int k = l + 64 * i; o[k] = (v[i] - mu) * rstd * gam[k] + bet[k]; }
}

// ---------------- cumsum over t (block per batch, thread per feature) ----------------
__global__ void k_cumsum(const float* __restrict__ tr, float* __restrict__ cs) {
    int b = blockIdx.x, f = threadIdx.x;  // 512 threads
    cs[((size_t)b * 121) * 512 + f] = 0.f;
    const float* src = tr + ((size_t)b * 120) * 512 + f;
    float* dst = cs + ((size_t)b * 121 + 1) * 512 + f;
    float run = 0.f;
    for (int t0 = 0; t0 < 120; t0 += 8) {
        float v[8];
        #pragma unroll
        for (int i = 0; i < 8; ++i) v[i] = src[(size_t)(t0 + i) * 512];
        #pragma unroll
        for (int i = 0; i < 8; ++i) { run += v[i]; dst[(size_t)(t0 + i) * 512] = run; }
    }
}

// ---------------- spans + label GEMM (wave per span) ----------------
__global__ void __launch_bounds__(256) k_span(const float* __restrict__ cs,
                                              const float* __restrict__ lw,
                                              const float* __restrict__ lbias,
                                              float* __restrict__ out) {
    __shared__ float wl[20][512];
    for (int idx = threadIdx.x; idx < 20 * 512; idx += 256) {
        int c = idx >> 9, k = idx & 511;
        wl[c][k] = lw[(size_t)k * 20 + c];
    }
    __syncthreads();
    int w = threadIdx.x >> 6, l = threadIdx.x & 63;
    int nw = gridDim.x * 4;
    for (int sp = blockIdx.x * 4 + w; sp < NSPAN; sp += nw) {
        int b = sp / 1155, s = sp - b * 1155;
        int beg, len;
        if (s < 1110) { beg = s / 10; len = s - beg * 10 + 1; }
        else {
            int t2 = s - 1110; beg = 111; int ll = 9;
            while (t2 >= ll) { t2 -= ll; --ll; ++beg; }
            len = t2 + 1;
        }
        int end = beg + len;
        const float* ce = cs + ((size_t)b * 121 + end) * 512;
        const float* cb = cs + ((size_t)b * 121 + beg) * 512;
        float inv = 1.f / (float)len;
        float p[20];
        #pragma unroll
        for (int c = 0; c < 20; ++c) p[c] = 0.f;
        #pragma unroll
        for (int i = 0; i < 8; ++i) {
            int k = l + 64 * i;
            float d = (ce[k] - cb[k]) * inv;
            #pragma unroll
            for (int c = 0; c < 20; ++c) p[c] += d * wl[c][k];
        }
        #pragma unroll
        for (int off = 32; off; off >>= 1) {
            #pragma unroll
            for (int c = 0; c < 20; ++c) p[c] += __shfl_xor(p[c], off);
        }
        if (l == 0) {
            float* o = out + (size_t)sp * 20;
            #pragma unroll
            for (int c = 0; c < 20; ++c) o[c] = p[c] + lbias[c];
        }
    }
}

// ---------------- column-wise logsumexp over 36960 rows ----------------
__global__ void __launch_bounds__(256) k_lsepart(const float* __restrict__ logits,
                                                 float2* __restrict__ part) {
    float m[20], sm[20];
    #pragma unroll
    for (int c = 0; c < 20; ++c) { m[c] = -1e30f; sm[c] = 0.f; }
    for (int row = blockIdx.x * 256 + threadIdx.x; row < NSPAN; row += gridDim.x * 256) {
        const float* r = logits + (size_t)row * 20;
        #pragma unroll
        for (int c = 0; c < 20; ++c) {
            float x = r[c];
            float nm = fmaxf(m[c], x);
            sm[c] = sm[c] * expf(m[c] - nm) + expf(x - nm);
            m[c] = nm;
        }
    }
    __shared__ float2 red[256][20];
    #pragma unroll
    for (int c = 0; c < 20; ++c) red[threadIdx.x][c] = make_float2(m[c], sm[c]);
    __syncthreads();
    for (int st = 128; st; st >>= 1) {
        if (threadIdx.x < st) {
            #pragma unroll
            for (int c = 0; c < 20; ++c) {
                float2 a = red[threadIdx.x][c], b = red[threadIdx.x + st][c];
                float nm = fmaxf(a.x, b.x);
                float ss = a.y * expf(a.x - nm) + b.y * expf(b.x - nm);
                red[threadIdx.x][c] = make_float2(nm, ss);
            }
        }
        __syncthreads();
    }
    if (threadIdx.x < 20) part[(size_t)blockIdx.x * 20 + threadIdx.x] = red[0][threadIdx.x];
}

__global__ void k_lsefin(const float2* __restrict__ part, int nparts, float* __restrict__ lse) {
    int c = threadIdx.x;
    if (c >= 20) return;
    float m = -1e30f, s = 0.f;
    for (int i = 0; i < nparts; ++i) {
        float2 a = part[(size_t)i * 20 + c];
        float nm = fmaxf(m, a.x);
        s = s * expf(m - nm) + a.y * expf(a.x - nm);
        m = nm;
    }
    lse[c] = m + logf(s);
}

__global__ void k_sub(float* __restrict__ out, const float* __restrict__ lse) {
    int i = blockIdx.x * 256 + threadIdx.x;
    if (i < NSPAN * 20) out[i] -= lse[i % 20];
}

// ---------------- launch ----------------
extern "C" void kernel_launch(void* const* d_in, const int* in_sizes, int n_in,
                              void* d_out, int out_size, void* d_ws, size_t ws_size,
                              hipStream_t stream) {
    (void)in_sizes; (void)n_in; (void)out_size; (void)ws_size;
    const int*   tokens = (const int*)  d_in[0];
    const float* emb    = (const float*)d_in[1];
    const float* w_ih_f = (const float*)d_in[2];
    const float* w_hh_f = (const float*)d_in[3];
    const float* b_ih_f = (const float*)d_in[4];
    const float* b_hh_f = (const float*)d_in[5];
    const float* w_ih_b = (const float*)d_in[6];
    const float* w_hh_b = (const float*)d_in[7];
    const float* b_ih_b = (const float*)d_in[8];
    const float* b_hh_b = (const float*)d_in[9];
    const float* lin1_w = (const float*)d_in[10];
    const float* lin1_b = (const float*)d_in[11];
    const float* lin2_w = (const float*)d_in[12];
    const float* lin2_b = (const float*)d_in[13];
    const float* ln_g   = (const float*)d_in[14];
    const float* ln_b   = (const float*)d_in[15];
    const float* label_w= (const float*)d_in[16];
    const float* label_b= (const float*)d_in[17];
    float* out = (float*)d_out;

    char* ws = (char*)d_ws;
    size_t off = 0;
    auto alloc = [&](size_t bytes) { char* p = ws + off; off += (bytes + 255) & ~size_t(255); return p; };
    // persistent-lifetime regions (~57 MB total; R2's proven-fit was 76.9 MB)
    short*  xbf   = (short*)alloc(3840ull * 256 * 2);
    short*  wihbf = (short*)alloc(4096ull * 256 * 2);
    short*  whhbf = (short*)alloc(2ull * 2048 * 512 * 2);   // dead after k_lstm
    short*  l1wbf = (short*)alloc(512ull * 1024 * 2);
    short*  l2wbf = (short*)alloc(512ull * 512 * 2);
    float*  biasc = (float*)alloc(4096ull * 4);
    short*  xg    = (short*)alloc(120ull * 4096 * 32 * 2);  // dead after k_lstm
    short*  hzero = (short*)alloc(32ull * 512 * 2);
    short*  hsteps= (short*)alloc(2ull * 120 * 32 * 512 * 2); // dead after k_lstm
    short*  rnn   = (short*)alloc(3840ull * 1024 * 2);
    int*    flags = (int*)  alloc(2ull * 120 * 32 * 4);
    float2* part  = (float2*)alloc(120ull * 20 * 8);
    float*  lse   = (float*)alloc(256);
    // overlays onto dead regions (strict stream ordering guarantees safety)
    short*  h1    = (short*)whhbf;          // 3.93 MB <= 4.19 MB, written after k_lstm
    float*  h2    = (float*)hsteps;         // 7.86 MB == 7.86 MB, written after k_lstm
    float*  tr    = (float*)xg;             // 7.86 MB <= 31.4 MB, written after k_lstm
    float*  cs    = (float*)((char*)xg + 8ull * 1024 * 1024);  // 7.93 MB, inside xg

    hipMemsetAsync(hzero, 0x00, 32ull * 512 * 2, stream);
    hipMemsetAsync(flags, 0x00, 2ull * 120 * 32 * 4, stream);

    k_gather<<<3840, 256, 0, stream>>>(tokens, emb, xbf);
    int n8;
    n8 = 2048 * 256 / 8; k_convert<<<(n8 + 255) / 256, 256, 0, stream>>>(w_ih_f, wihbf, n8);
    n8 = 2048 * 256 / 8; k_convert<<<(n8 + 255) / 256, 256, 0, stream>>>(w_ih_b, wihbf + 2048ull * 256, n8);
    n8 = 2048 * 512 / 8; k_convert<<<(n8 + 255) / 256, 256, 0, stream>>>(w_hh_f, whhbf, n8);
    n8 = 2048 * 512 / 8; k_convert<<<(n8 + 255) / 256, 256, 0, stream>>>(w_hh_b, whhbf + 2048ull * 512, n8);
    n8 = 512 * 1024 / 8; k_convert<<<(n8 + 255) / 256, 256, 0, stream>>>(lin1_w, l1wbf, n8);
    n8 = 512 * 512 / 8;  k_convert<<<(n8 + 255) / 256, 256, 0, stream>>>(lin2_w, l2wbf, n8);
    k_biascomb<<<16, 256, 0, stream>>>(b_ih_f, b_hh_f, b_ih_b, b_hh_b, biasc);

    // xg[t][g(4096)][b] = x @ [w_ih_f; w_ih_b]^T + (b_ih + b_hh)
    k_gemm<2><<<dim3(60, 64), 256, 0, stream>>>(xbf, wihbf, biasc, nullptr, xg, 4096, 256);
    // recurrence -> rnn[b*T+t][1024] (fwd | bwd)
    k_lstm<<<64, 256, 0, stream>>>(xg, whhbf, hzero, hsteps, rnn, flags);
    // lin1 + relu -> bf16   (h1 overlays whhbf)
    k_gemm<1><<<dim3(60, 8), 256, 0, stream>>>(rnn, l1wbf, lin1_b, nullptr, h1, 512, 1024);
    // lin2 -> fp32          (h2 overlays hsteps)
    k_gemm<0><<<dim3(60, 8), 256, 0, stream>>>(h1, l2wbf, lin2_b, h2, nullptr, 512, 512);
    k_ln<<<960, 256, 0, stream>>>(h2, ln_g, ln_b, tr);
    k_cumsum<<<32, 512, 0, stream>>>(tr, cs);
    k_span<<<512, 256, 0, stream>>>(cs, label_w, label_b, out);
    k_lsepart<<<120, 256, 0, stream>>>(out, part);
    k_lsefin<<<1, 32, 0, stream>>>(part, 120, lse);
    k_sub<<<(NSPAN * 20 + 255) / 256, 256, 0, stream>>>(out, lse);
}